// Round 2
// baseline (1016.342 us; speedup 1.0000x reference)
//
#include <hip/hip_runtime.h>
#include <cstdint>

// Problem constants (B=2, N=4096, NIN=NH=128)
#define NTOK 4096
#define DD   128
#define CAP  128   // max edges/row; binom(4096,0.01) mean 41, P(>127) ~ 1e-40

// ---------------- threefry2x32, JAX partitionable path (default since 0.4.30)
// key(42) => (k0,k1)=(0,42); ks2 = 0^42^0x1BD11BDA = 0x1BD11BF0
// per flat index i (u64, here <2^25): counter words (hi,lo)=(0,i);
// bits = out0 ^ out1; uniform = bitcast((bits>>9)|0x3F800000) - 1; keep = u<0.9
__device__ __forceinline__ void tf_round(uint32_t& x0, uint32_t& x1, int r) {
  x0 += x1;
  x1 = (x1 << r) | (x1 >> (32 - r));
  x1 ^= x0;
}

__device__ __forceinline__ float tf_uniform(uint32_t i) {
  const uint32_t ks1 = 42u, ks2 = 0x1BD11BF0u;
  uint32_t x0 = 0u;          // counts_hi (=0) + ks0 (=0)
  uint32_t x1 = i + ks1;     // counts_lo + ks1
  tf_round(x0,x1,13); tf_round(x0,x1,15); tf_round(x0,x1,26); tf_round(x0,x1,6);
  x0 += ks1; x1 += ks2 + 1u;
  tf_round(x0,x1,17); tf_round(x0,x1,29); tf_round(x0,x1,16); tf_round(x0,x1,24);
  x0 += ks2; x1 += 0u + 2u;
  tf_round(x0,x1,13); tf_round(x0,x1,15); tf_round(x0,x1,26); tf_round(x0,x1,6);
  x0 += 0u; x1 += ks1 + 3u;
  tf_round(x0,x1,17); tf_round(x0,x1,29); tf_round(x0,x1,16); tf_round(x0,x1,24);
  x0 += ks1; x1 += ks2 + 4u;
  tf_round(x0,x1,13); tf_round(x0,x1,15); tf_round(x0,x1,26); tf_round(x0,x1,6);
  x0 += ks2; x1 += 0u + 5u;
  uint32_t bits = x0 ^ x1;
  return __uint_as_float((bits >> 9) | 0x3F800000u) - 1.0f;
}

// ---------------- K1: fts = seq1@W_fc1, fts2 = seq1@W_fc2 (16 rows/block) ----
__global__ __launch_bounds__(256) void k_fc(const float* __restrict__ seq1,
    const float* __restrict__ W1, const float* __restrict__ W2,
    float* __restrict__ fts, float* __restrict__ fts2) {
  __shared__ float sS[16][DD];
  const int tid = threadIdx.x;
  const size_t r0 = (size_t)blockIdx.x * 16;
  for (int i = tid; i < 16*DD/4; i += 256)
    reinterpret_cast<float4*>(&sS[0][0])[i] =
        reinterpret_cast<const float4*>(seq1 + r0*DD)[i];
  __syncthreads();
  const int cc = tid & 127, g = tid >> 7;
  float a1_[8] = {}, a2_[8] = {};
  for (int kk = 0; kk < DD; ++kk) {
    float w1 = W1[kk*DD + cc], w2 = W2[kk*DD + cc];
#pragma unroll
    for (int r = 0; r < 8; ++r) {
      float sv = sS[2*r + g][kk];
      a1_[r] += sv * w1; a2_[r] += sv * w2;
    }
  }
#pragma unroll
  for (int r = 0; r < 8; ++r) {
    fts [(r0 + 2*r + g)*DD + cc] = a1_[r];
    fts2[(r0 + 2*r + g)*DD + cc] = a2_[r];
  }
}

// ---------------- K2: edge extraction (deterministic, sorted) + out=adj@fts --
__global__ __launch_bounds__(256) void k_adj(const float* __restrict__ adj,
    const float* __restrict__ fts, float* __restrict__ outg,
    int* __restrict__ e_idx, int* __restrict__ e_cnt) {
  const int row = blockIdx.x;            // b*N + m
  const int b = row >> 12;
  const int tid = threadIdx.x;
  __shared__ float sA[NTOK];
  __shared__ int   sc[256];
  __shared__ int   sIdx[CAP];
  __shared__ float sVal[CAP];
  __shared__ float sPart[2][DD];
  const float* arow = adj + (size_t)row * NTOK;
  for (int i = tid; i < NTOK/4; i += 256)
    reinterpret_cast<float4*>(sA)[i] = reinterpret_cast<const float4*>(arow)[i];
  __syncthreads();
  const int base = tid * 16;
  int cnt = 0;
#pragma unroll
  for (int j = 0; j < 16; ++j) cnt += (sA[base + j] > 0.f) ? 1 : 0;
  sc[tid] = cnt;
  __syncthreads();
  for (int off = 1; off < 256; off <<= 1) {   // Hillis-Steele inclusive scan
    int v = (tid >= off) ? sc[tid - off] : 0;
    __syncthreads();
    sc[tid] += v;
    __syncthreads();
  }
  int w = sc[tid] - cnt;
  const int total = sc[255];
  const int c = min(total, CAP);
#pragma unroll
  for (int j = 0; j < 16; ++j) {
    float a = sA[base + j];
    if (a > 0.f) { if (w < CAP) { sIdx[w] = base + j; sVal[w] = a; } ++w; }
  }
  __syncthreads();
  if (tid == 0) e_cnt[row] = c;
  for (int t = tid; t < c; t += 256) e_idx[(size_t)row*CAP + t] = sIdx[t];
  // out row = sum_e val_e * fts[n_e, :]
  const float* fb = fts + (size_t)b * NTOK * DD;
  const int col = tid & 127, h = tid >> 7;
  float accv = 0.f;
  for (int e = h; e < c; e += 2)
    accv += sVal[e] * fb[(size_t)sIdx[e]*DD + col];
  sPart[h][col] = accv;
  __syncthreads();
  if (tid < DD) outg[(size_t)row*DD + tid] = sPart[0][tid] + sPart[1][tid];
}

// ---------------- K3: q,k = l2norm(out@Wq/Wk), div partials (16 rows/block) --
__global__ __launch_bounds__(256) void k_qk(const float* __restrict__ outg,
    const float* __restrict__ Wq, const float* __restrict__ Wk,
    float* __restrict__ qo, float* __restrict__ ko,
    float* __restrict__ divpart) {
  __shared__ float sO[16][DD], sQ[16][DD], sK[16][DD];
  __shared__ float sDv[16];
  const int tid = threadIdx.x;
  const size_t r0 = (size_t)blockIdx.x * 16;
  for (int i = tid; i < 16*DD/4; i += 256)
    reinterpret_cast<float4*>(&sO[0][0])[i] =
        reinterpret_cast<const float4*>(outg + r0*DD)[i];
  __syncthreads();
  const int cc = tid & 127, g = tid >> 7;
  float aq[8] = {}, ak[8] = {};
  for (int kk = 0; kk < DD; ++kk) {
    float wq = Wq[kk*DD + cc], wk = Wk[kk*DD + cc];
#pragma unroll
    for (int r = 0; r < 8; ++r) {
      float ov = sO[2*r + g][kk];
      aq[r] += ov * wq; ak[r] += ov * wk;
    }
  }
#pragma unroll
  for (int r = 0; r < 8; ++r) { sQ[2*r+g][cc] = aq[r]; sK[2*r+g][cc] = ak[r]; }
  __syncthreads();
  const int rr = tid >> 4, l = tid & 15;
  float sq = 0.f, sk = 0.f;
  for (int cix = l; cix < DD; cix += 16) {
    float qv = sQ[rr][cix], kv = sK[rr][cix];
    sq += qv*qv; sk += kv*kv;
  }
#pragma unroll
  for (int o = 8; o; o >>= 1) { sq += __shfl_xor(sq, o, 16); sk += __shfl_xor(sk, o, 16); }
  const float iq = 1.f / fmaxf(sqrtf(sq), 1e-12f);
  const float ik = 1.f / fmaxf(sqrtf(sk), 1e-12f);
  float dv = 0.f;
  for (int cix = l; cix < DD; cix += 16) {
    float qn = sQ[rr][cix] * iq, kn = sK[rr][cix] * ik;
    qo[(r0+rr)*DD + cix] = qn;
    ko[(r0+rr)*DD + cix] = kn;
    float d = qn - kn; dv += d*d;
  }
#pragma unroll
  for (int o = 8; o; o >>= 1) dv += __shfl_xor(dv, o, 16);
  if (l == 0) sDv[rr] = dv;
  __syncthreads();
  if (tid == 0) {
    float s = 0.f;
#pragma unroll
    for (int r = 0; r < 16; ++r) s += sDv[r];
    divpart[blockIdx.x] = s;  // deterministic: per-block slot, summed later
  }
}

// ---------------- K4: sparse masked softmax + dropout + agg = attn@out ------
__global__ __launch_bounds__(256) void k_attn(const float* __restrict__ qo,
    const float* __restrict__ ko, const float* __restrict__ outg,
    const int* __restrict__ e_idx, const int* __restrict__ e_cnt,
    float* __restrict__ agg) {
  const int row = blockIdx.x;
  const int b = row >> 12;
  const int tid = threadIdx.x;
  __shared__ float sQ[DD];
  __shared__ int   sIdx[CAP];
  __shared__ float sP[CAP];
  __shared__ float sSum;
  __shared__ float sPart[2][DD];
  const int c = min(e_cnt[row], CAP);
  if (tid < DD) sQ[tid] = qo[(size_t)row*DD + tid];
  for (int t = tid; t < c; t += 256) sIdx[t] = e_idx[(size_t)row*CAP + t];
  __syncthreads();
  const int wv = tid >> 6, ln = tid & 63;
  const float* kb = ko + (size_t)b * NTOK * DD;
  for (int e = wv; e < c; e += 4) {          // one wave per edge dot
    const float* kr = kb + (size_t)sIdx[e] * DD;
    float p = sQ[2*ln] * kr[2*ln] + sQ[2*ln+1] * kr[2*ln+1];
#pragma unroll
    for (int o = 32; o; o >>= 1) p += __shfl_xor(p, o, 64);
    if (ln == 0) sP[e] = p;
  }
  __syncthreads();
  if (wv == 0) {                             // softmax max+sum by wave 0
    float mx = -3.0e38f;
    for (int e = ln; e < c; e += 64) mx = fmaxf(mx, sP[e]);
#pragma unroll
    for (int o = 32; o; o >>= 1) mx = fmaxf(mx, __shfl_xor(mx, o, 64));
    float sum = 0.f;
    for (int e = ln; e < c; e += 64) { float ex = expf(sP[e] - mx); sP[e] = ex; sum += ex; }
#pragma unroll
    for (int o = 32; o; o >>= 1) sum += __shfl_xor(sum, o, 64);
    if (ln == 0) sSum = sum;
  }
  __syncthreads();
  const float inv = 1.f / (sSum * 0.9f);     // softmax /sum, dropout /0.9
  for (int t = tid; t < c; t += 256) {
    uint32_t fi = ((uint32_t)row << 12) | (uint32_t)sIdx[t];
    sP[t] = (tf_uniform(fi) < 0.9f) ? sP[t] * inv : 0.f;
  }
  __syncthreads();
  const int col = tid & 127, h = tid >> 7;
  const float* ob = outg + (size_t)b * NTOK * DD;
  float accv = 0.f;
  for (int e = h; e < c; e += 2)
    accv += sP[e] * ob[(size_t)sIdx[e]*DD + col];
  sPart[h][col] = accv;
  __syncthreads();
  if (tid < DD) agg[(size_t)row*DD + tid] = sPart[0][tid] + sPart[1][tid];
}

// ---------------- K5: h1 = prelu(prelu(agg@Wv1)@Wv2), h1n, div write --------
__global__ __launch_bounds__(256) void k_v(const float* __restrict__ agg,
    const float* __restrict__ Wv1, const float* __restrict__ Wv2,
    const float* __restrict__ av_, const float* __restrict__ a1_,
    float* __restrict__ h1o, float* __restrict__ h1n,
    const float* __restrict__ divpart, float* __restrict__ divout) {
  __shared__ float sA[16][DD];
  __shared__ float sT[16][DD];
  const int tid = threadIdx.x;
  const size_t r0 = (size_t)blockIdx.x * 16;
  for (int i = tid; i < 16*DD/4; i += 256)
    reinterpret_cast<float4*>(&sA[0][0])[i] =
        reinterpret_cast<const float4*>(agg + r0*DD)[i];
  __syncthreads();
  const int cc = tid & 127, g = tid >> 7;
  const float av = av_[0], a1v = a1_[0];
  float t_[8] = {};
  for (int kk = 0; kk < DD; ++kk) {
    float w = Wv1[kk*DD + cc];
#pragma unroll
    for (int r = 0; r < 8; ++r) t_[r] += sA[2*r + g][kk] * w;
  }
#pragma unroll
  for (int r = 0; r < 8; ++r) { float x = t_[r]; sT[2*r+g][cc] = (x >= 0.f) ? x : av * x; }
  __syncthreads();
  float v_[8] = {};
  for (int kk = 0; kk < DD; ++kk) {
    float w = Wv2[kk*DD + cc];
#pragma unroll
    for (int r = 0; r < 8; ++r) v_[r] += sT[2*r + g][kk] * w;
  }
  __syncthreads();                 // sA reads (matmul1) finished long ago; reuse it
#pragma unroll
  for (int r = 0; r < 8; ++r) { float x = v_[r]; sA[2*r+g][cc] = (x >= 0.f) ? x : a1v * x; }
  __syncthreads();
  const int rr = tid >> 4, l = tid & 15;
  float ss = 0.f;
  for (int cix = l; cix < DD; cix += 16) { float hv = sA[rr][cix]; ss += hv*hv; }
#pragma unroll
  for (int o = 8; o; o >>= 1) ss += __shfl_xor(ss, o, 16);
  const float innv = 1.f / fmaxf(sqrtf(ss), 1e-12f);
  for (int cix = l; cix < DD; cix += 16) {
    float hv = sA[rr][cix];
    h1o[(r0+rr)*DD + cix] = hv;
    h1n[(r0+rr)*DD + cix] = hv * innv;
  }
  if (blockIdx.x == 0 && tid == 0) {       // deterministic div_loss finalize
    float s = 0.f;
    for (int i = 0; i < 512; ++i) s += divpart[i];
    divout[0] = s * (1.f / 8192.f);
  }
}

// ---------------- K6: h2 = prelu(diff@fts2), h2n  (32x128 tile, K-step 64) --
__global__ __launch_bounds__(256) void k_diff(const float* __restrict__ diff,
    const float* __restrict__ fts2, const float* __restrict__ a2_,
    float* __restrict__ h2o, float* __restrict__ h2n) {
  constexpr int BM = 32, KT = 64;
  __shared__ float sD[BM][KT];
  __shared__ float sF[KT][DD];
  const int blk = blockIdx.x;         // 256 blocks
  const int b = blk >> 7;
  const int m0 = (blk & 127) * BM;
  const int tid = threadIdx.x;
  const float* Dp = diff + (size_t)b*NTOK*NTOK + (size_t)m0*NTOK;
  const float* Fp = fts2 + (size_t)b*NTOK*DD;
  const int rg = tid >> 5, c0 = tid & 31;
  float acc[4][4] = {};
  for (int k0 = 0; k0 < NTOK; k0 += KT) {
    for (int i = tid; i < BM*KT/4; i += 256) {
      int r = i >> 4, kq = i & 15;
      reinterpret_cast<float4*>(&sD[r][0])[kq] =
          *reinterpret_cast<const float4*>(Dp + (size_t)r*NTOK + k0 + kq*4);
    }
    for (int i = tid; i < KT*DD/4; i += 256) {
      int rr2 = i >> 5, cq = i & 31;
      reinterpret_cast<float4*>(&sF[rr2][0])[cq] =
          *reinterpret_cast<const float4*>(Fp + (size_t)(k0+rr2)*DD + cq*4);
    }
    __syncthreads();
    for (int kk = 0; kk < KT; ++kk) {
      float4 fv = *reinterpret_cast<const float4*>(&sF[kk][4*c0]);
#pragma unroll
      for (int i2 = 0; i2 < 4; ++i2) {
        float dvv = sD[rg + 8*i2][kk];
        acc[i2][0] += dvv * fv.x; acc[i2][1] += dvv * fv.y;
        acc[i2][2] += dvv * fv.z; acc[i2][3] += dvv * fv.w;
      }
    }
    __syncthreads();
  }
  const float a2v = a2_[0];
#pragma unroll
  for (int i2 = 0; i2 < 4; ++i2) {
    float hrow[4]; float ss = 0.f;
#pragma unroll
    for (int j = 0; j < 4; ++j) {
      float x = acc[i2][j]; x = (x >= 0.f) ? x : a2v * x; hrow[j] = x; ss += x*x;
    }
#pragma unroll
    for (int o = 16; o; o >>= 1) ss += __shfl_xor(ss, o, 32);  // 32 lanes share row
    const float innv = 1.f / fmaxf(sqrtf(ss), 1e-12f);
    const size_t grow = (size_t)(b*NTOK + m0 + rg + 8*i2) * DD;
    float4 hv4 = make_float4(hrow[0], hrow[1], hrow[2], hrow[3]);
    float4 hn4 = make_float4(hrow[0]*innv, hrow[1]*innv, hrow[2]*innv, hrow[3]*innv);
    *reinterpret_cast<float4*>(&h2o[grow + 4*c0]) = hv4;
    *reinterpret_cast<float4*>(&h2n[grow + 4*c0]) = hn4;
  }
}

// ---------------- K7: ret = h1n @ h2n^T  (64x64 tiles, K=128) ---------------
__global__ __launch_bounds__(256) void k_ret(const float* __restrict__ h1n,
    const float* __restrict__ h2n, float* __restrict__ ret) {
  __shared__ float sA[64][132];
  __shared__ float sB[64][132];
  const int blk = blockIdx.x;           // 2 * 64 * 64 = 8192
  const int b = blk >> 12;
  const int t = blk & 4095;
  const int i0 = (t >> 6) * 64, j0 = (t & 63) * 64;
  const int tid = threadIdx.x;
  const float* Ap = h1n + (size_t)b*NTOK*DD + (size_t)i0*DD;
  const float* Bp = h2n + (size_t)b*NTOK*DD + (size_t)j0*DD;
  for (int i = tid; i < 64*DD/4; i += 256) {
    int r = i >> 5, cq = i & 31;
    *reinterpret_cast<float4*>(&sA[r][cq*4]) =
        *reinterpret_cast<const float4*>(Ap + (size_t)r*DD + cq*4);
    *reinterpret_cast<float4*>(&sB[r][cq*4]) =
        *reinterpret_cast<const float4*>(Bp + (size_t)r*DD + cq*4);
  }
  __syncthreads();
  const int tr = tid >> 4, tc = tid & 15;   // rows tr+16i, cols 4tc+j
  float acc[4][4] = {};
  for (int kd = 0; kd < DD; kd += 4) {
    float4 a_[4], b_[4];
#pragma unroll
    for (int i2 = 0; i2 < 4; ++i2)
      a_[i2] = *reinterpret_cast<const float4*>(&sA[tr + 16*i2][kd]);
#pragma unroll
    for (int j = 0; j < 4; ++j)
      b_[j] = *reinterpret_cast<const float4*>(&sB[4*tc + j][kd]);
#pragma unroll
    for (int i2 = 0; i2 < 4; ++i2)
#pragma unroll
      for (int j = 0; j < 4; ++j)
        acc[i2][j] += a_[i2].x*b_[j].x + a_[i2].y*b_[j].y
                    + a_[i2].z*b_[j].z + a_[i2].w*b_[j].w;
  }
  float* rp = ret + (size_t)b*NTOK*NTOK;
#pragma unroll
  for (int i2 = 0; i2 < 4; ++i2) {
    float4 v = make_float4(acc[i2][0], acc[i2][1], acc[i2][2], acc[i2][3]);
    *reinterpret_cast<float4*>(&rp[(size_t)(i0 + tr + 16*i2)*NTOK + j0 + 4*tc]) = v;
  }
}

// ---------------- launch ----------------------------------------------------
extern "C" void kernel_launch(void* const* d_in, const int* in_sizes, int n_in,
                              void* d_out, int out_size, void* d_ws, size_t ws_size,
                              hipStream_t stream) {
  const float* seq1 = (const float*)d_in[0];
  const float* adj  = (const float*)d_in[2];
  const float* diff = (const float*)d_in[3];
  const float* Wfc1 = (const float*)d_in[7];
  const float* a1   = (const float*)d_in[8];
  const float* Wq   = (const float*)d_in[9];
  const float* Wk   = (const float*)d_in[10];
  const float* Wv1  = (const float*)d_in[11];
  const float* av   = (const float*)d_in[12];
  const float* Wv2  = (const float*)d_in[13];
  const float* Wfc2 = (const float*)d_in[14];
  const float* a2   = (const float*)d_in[15];
  float* out = (float*)d_out;
  float* ws  = (float*)d_ws;

  const size_t BN  = (size_t)2 * NTOK;          // 8192 rows
  const size_t RND = BN * DD;                   // 1048576
  float* fts   = ws;
  float* fts2  = ws + RND;
  float* outg  = ws + 2*RND;
  float* q     = ws + 3*RND;
  float* k     = ws + 4*RND;
  float* agg   = ws + 5*RND;
  float* h1n   = ws + 6*RND;
  float* h2n   = ws + 7*RND;
  float* divp  = ws + 8*RND;                    // 512 floats
  int*   e_cnt = (int*)(ws + 8*RND + 512);      // 8192 ints
  int*   e_idx = (int*)(ws + 8*RND + 512 + BN); // 8192*CAP ints

  const size_t OFF_H1  = (size_t)2 * NTOK * NTOK;   // 33554432
  const size_t OFF_H2  = OFF_H1 + RND;              // 34603008
  const size_t OFF_DIV = OFF_H2 + RND;              // 35651584

  k_fc  <<<512,  256, 0, stream>>>(seq1, Wfc1, Wfc2, fts, fts2);
  k_adj <<<8192, 256, 0, stream>>>(adj, fts, outg, e_idx, e_cnt);
  k_qk  <<<512,  256, 0, stream>>>(outg, Wq, Wk, q, k, divp);
  k_attn<<<8192, 256, 0, stream>>>(q, k, outg, e_idx, e_cnt, agg);
  k_v   <<<512,  256, 0, stream>>>(agg, Wv1, Wv2, av, a1,
                                   out + OFF_H1, h1n, divp, out + OFF_DIV);
  k_diff<<<256,  256, 0, stream>>>(diff, fts2, a2, out + OFF_H2, h2n);
  k_ret <<<8192, 256, 0, stream>>>(h1n, h2n, out);
}

// Round 3
// 709.289 us; speedup vs baseline: 1.4329x; 1.4329x over previous
//
#include <hip/hip_runtime.h>
#include <cstdint>

// Problem constants (B=2, N=4096, NIN=NH=128)
#define NTOK 4096
#define DD   128
#define CAP  128   // max edges/row; binom(4096,0.01) mean 41, P(>127) ~ 1e-40

typedef __attribute__((ext_vector_type(8))) short short8v;   // 8 bf16 (4 VGPR)
typedef __attribute__((ext_vector_type(4))) float f32x4;     // MFMA C/D

__device__ __forceinline__ uint16_t f2bf(float x) {          // truncate f32->bf16
  return (uint16_t)(__float_as_uint(x) >> 16);
}

// ---------------- threefry2x32, JAX partitionable path (verified R2) --------
__device__ __forceinline__ void tf_round(uint32_t& x0, uint32_t& x1, int r) {
  x0 += x1;
  x1 = (x1 << r) | (x1 >> (32 - r));
  x1 ^= x0;
}

__device__ __forceinline__ float tf_uniform(uint32_t i) {
  const uint32_t ks1 = 42u, ks2 = 0x1BD11BF0u;
  uint32_t x0 = 0u;          // counts_hi (=0) + ks0 (=0)
  uint32_t x1 = i + ks1;     // counts_lo + ks1
  tf_round(x0,x1,13); tf_round(x0,x1,15); tf_round(x0,x1,26); tf_round(x0,x1,6);
  x0 += ks1; x1 += ks2 + 1u;
  tf_round(x0,x1,17); tf_round(x0,x1,29); tf_round(x0,x1,16); tf_round(x0,x1,24);
  x0 += ks2; x1 += 0u + 2u;
  tf_round(x0,x1,13); tf_round(x0,x1,15); tf_round(x0,x1,26); tf_round(x0,x1,6);
  x0 += 0u; x1 += ks1 + 3u;
  tf_round(x0,x1,17); tf_round(x0,x1,29); tf_round(x0,x1,16); tf_round(x0,x1,24);
  x0 += ks1; x1 += ks2 + 4u;
  tf_round(x0,x1,13); tf_round(x0,x1,15); tf_round(x0,x1,26); tf_round(x0,x1,6);
  x0 += ks2; x1 += 0u + 5u;
  uint32_t bits = x0 ^ x1;
  return __uint_as_float((bits >> 9) | 0x3F800000u) - 1.0f;
}

// ---------------- K1: fts = seq1@W_fc1, fts2 = seq1@W_fc2 (16 rows/block) ----
__global__ __launch_bounds__(256) void k_fc(const float* __restrict__ seq1,
    const float* __restrict__ W1, const float* __restrict__ W2,
    float* __restrict__ fts, float* __restrict__ fts2) {
  __shared__ float sS[16][DD];
  const int tid = threadIdx.x;
  const size_t r0 = (size_t)blockIdx.x * 16;
  for (int i = tid; i < 16*DD/4; i += 256)
    reinterpret_cast<float4*>(&sS[0][0])[i] =
        reinterpret_cast<const float4*>(seq1 + r0*DD)[i];
  __syncthreads();
  const int cc = tid & 127, g = tid >> 7;
  float a1_[8] = {}, a2_[8] = {};
  for (int kk = 0; kk < DD; ++kk) {
    float w1 = W1[kk*DD + cc], w2 = W2[kk*DD + cc];
#pragma unroll
    for (int r = 0; r < 8; ++r) {
      float sv = sS[2*r + g][kk];
      a1_[r] += sv * w1; a2_[r] += sv * w2;
    }
  }
#pragma unroll
  for (int r = 0; r < 8; ++r) {
    fts [(r0 + 2*r + g)*DD + cc] = a1_[r];
    fts2[(r0 + 2*r + g)*DD + cc] = a2_[r];
  }
}

// ---------------- K1b: fts2T[b][col][k] bf16 <- fts2[b][k][col] fp32 --------
__global__ __launch_bounds__(256) void k_prep(const float* __restrict__ fts2,
    uint16_t* __restrict__ fts2T) {
  __shared__ uint16_t sT[DD][72];     // 72-ushort stride: 144B = 9*16B aligned
  const int blk = blockIdx.x;         // 128 = b(2) x 64 node-tiles
  const int b = blk >> 6, nt = blk & 63;
  const int tid = threadIdx.x;
  const float* src = fts2 + ((size_t)b*NTOK + nt*64)*DD;
  for (int i = tid; i < 64*DD/4; i += 256) {
    int nd = i >> 5, c4 = (i & 31) * 4;
    float4 v = *reinterpret_cast<const float4*>(src + nd*DD + c4);
    sT[c4+0][nd] = f2bf(v.x); sT[c4+1][nd] = f2bf(v.y);
    sT[c4+2][nd] = f2bf(v.z); sT[c4+3][nd] = f2bf(v.w);
  }
  __syncthreads();
  for (int i = tid; i < 1024; i += 256) {
    int col = i >> 3, p = i & 7;
    *reinterpret_cast<int4*>(fts2T + ((size_t)b*DD + col)*NTOK + nt*64 + p*8) =
        *reinterpret_cast<const int4*>(&sT[col][p*8]);
  }
}

// ---------------- K2: edge extraction (deterministic, sorted) + out=adj@fts --
__global__ __launch_bounds__(256) void k_adj(const float* __restrict__ adj,
    const float* __restrict__ fts, float* __restrict__ outg,
    int* __restrict__ e_idx, int* __restrict__ e_cnt) {
  const int row = blockIdx.x;            // b*N + m
  const int b = row >> 12;
  const int tid = threadIdx.x;
  __shared__ float sA[NTOK];
  __shared__ int   sc[256];
  __shared__ int   sIdx[CAP];
  __shared__ float sVal[CAP];
  __shared__ float sPart[2][DD];
  const float* arow = adj + (size_t)row * NTOK;
  for (int i = tid; i < NTOK/4; i += 256)
    reinterpret_cast<float4*>(sA)[i] = reinterpret_cast<const float4*>(arow)[i];
  __syncthreads();
  const int base = tid * 16;
  int cnt = 0;
#pragma unroll
  for (int j = 0; j < 16; ++j) cnt += (sA[base + j] > 0.f) ? 1 : 0;
  sc[tid] = cnt;
  __syncthreads();
  for (int off = 1; off < 256; off <<= 1) {   // Hillis-Steele inclusive scan
    int v = (tid >= off) ? sc[tid - off] : 0;
    __syncthreads();
    sc[tid] += v;
    __syncthreads();
  }
  int w = sc[tid] - cnt;
  const int total = sc[255];
  const int c = min(total, CAP);
#pragma unroll
  for (int j = 0; j < 16; ++j) {
    float a = sA[base + j];
    if (a > 0.f) { if (w < CAP) { sIdx[w] = base + j; sVal[w] = a; } ++w; }
  }
  __syncthreads();
  if (tid == 0) e_cnt[row] = c;
  for (int t = tid; t < c; t += 256) e_idx[(size_t)row*CAP + t] = sIdx[t];
  // out row = sum_e val_e * fts[n_e, :]
  const float* fb = fts + (size_t)b * NTOK * DD;
  const int col = tid & 127, h = tid >> 7;
  float accv = 0.f;
  for (int e = h; e < c; e += 2)
    accv += sVal[e] * fb[(size_t)sIdx[e]*DD + col];
  sPart[h][col] = accv;
  __syncthreads();
  if (tid < DD) outg[(size_t)row*DD + tid] = sPart[0][tid] + sPart[1][tid];
}

// ---------------- K3: q,k = l2norm(out@Wq/Wk), div partials (16 rows/block) --
__global__ __launch_bounds__(256) void k_qk(const float* __restrict__ outg,
    const float* __restrict__ Wq, const float* __restrict__ Wk,
    float* __restrict__ qo, float* __restrict__ ko,
    float* __restrict__ divpart) {
  __shared__ float sO[16][DD], sQ[16][DD], sK[16][DD];
  __shared__ float sDv[16];
  const int tid = threadIdx.x;
  const size_t r0 = (size_t)blockIdx.x * 16;
  for (int i = tid; i < 16*DD/4; i += 256)
    reinterpret_cast<float4*>(&sO[0][0])[i] =
        reinterpret_cast<const float4*>(outg + r0*DD)[i];
  __syncthreads();
  const int cc = tid & 127, g = tid >> 7;
  float aq[8] = {}, ak[8] = {};
  for (int kk = 0; kk < DD; ++kk) {
    float wq = Wq[kk*DD + cc], wk = Wk[kk*DD + cc];
#pragma unroll
    for (int r = 0; r < 8; ++r) {
      float ov = sO[2*r + g][kk];
      aq[r] += ov * wq; ak[r] += ov * wk;
    }
  }
#pragma unroll
  for (int r = 0; r < 8; ++r) { sQ[2*r+g][cc] = aq[r]; sK[2*r+g][cc] = ak[r]; }
  __syncthreads();
  const int rr = tid >> 4, l = tid & 15;
  float sq = 0.f, sk = 0.f;
  for (int cix = l; cix < DD; cix += 16) {
    float qv = sQ[rr][cix], kv = sK[rr][cix];
    sq += qv*qv; sk += kv*kv;
  }
#pragma unroll
  for (int o = 8; o; o >>= 1) { sq += __shfl_xor(sq, o, 16); sk += __shfl_xor(sk, o, 16); }
  const float iq = 1.f / fmaxf(sqrtf(sq), 1e-12f);
  const float ik = 1.f / fmaxf(sqrtf(sk), 1e-12f);
  float dv = 0.f;
  for (int cix = l; cix < DD; cix += 16) {
    float qn = sQ[rr][cix] * iq, kn = sK[rr][cix] * ik;
    qo[(r0+rr)*DD + cix] = qn;
    ko[(r0+rr)*DD + cix] = kn;
    float d = qn - kn; dv += d*d;
  }
#pragma unroll
  for (int o = 8; o; o >>= 1) dv += __shfl_xor(dv, o, 16);
  if (l == 0) sDv[rr] = dv;
  __syncthreads();
  if (tid == 0) {
    float s = 0.f;
#pragma unroll
    for (int r = 0; r < 16; ++r) s += sDv[r];
    divpart[blockIdx.x] = s;  // deterministic: per-block slot, summed later
  }
}

// ---------------- K4: sparse masked softmax + dropout + agg = attn@out ------
__global__ __launch_bounds__(256) void k_attn(const float* __restrict__ qo,
    const float* __restrict__ ko, const float* __restrict__ outg,
    const int* __restrict__ e_idx, const int* __restrict__ e_cnt,
    float* __restrict__ agg) {
  const int row = blockIdx.x;
  const int b = row >> 12;
  const int tid = threadIdx.x;
  __shared__ float sQ[DD];
  __shared__ int   sIdx[CAP];
  __shared__ float sP[CAP];
  __shared__ float sSum;
  __shared__ float sPart[2][DD];
  const int c = min(e_cnt[row], CAP);
  if (tid < DD) sQ[tid] = qo[(size_t)row*DD + tid];
  for (int t = tid; t < c; t += 256) sIdx[t] = e_idx[(size_t)row*CAP + t];
  __syncthreads();
  const int wv = tid >> 6, ln = tid & 63;
  const float* kb = ko + (size_t)b * NTOK * DD;
  for (int e = wv; e < c; e += 4) {          // one wave per edge dot
    const float* kr = kb + (size_t)sIdx[e] * DD;
    float p = sQ[2*ln] * kr[2*ln] + sQ[2*ln+1] * kr[2*ln+1];
#pragma unroll
    for (int o = 32; o; o >>= 1) p += __shfl_xor(p, o, 64);
    if (ln == 0) sP[e] = p;
  }
  __syncthreads();
  if (wv == 0) {                             // softmax max+sum by wave 0
    float mx = -3.0e38f;
    for (int e = ln; e < c; e += 64) mx = fmaxf(mx, sP[e]);
#pragma unroll
    for (int o = 32; o; o >>= 1) mx = fmaxf(mx, __shfl_xor(mx, o, 64));
    float sum = 0.f;
    for (int e = ln; e < c; e += 64) { float ex = expf(sP[e] - mx); sP[e] = ex; sum += ex; }
#pragma unroll
    for (int o = 32; o; o >>= 1) sum += __shfl_xor(sum, o, 64);
    if (ln == 0) sSum = sum;
  }
  __syncthreads();
  const float inv = 1.f / (sSum * 0.9f);     // softmax /sum, dropout /0.9
  for (int t = tid; t < c; t += 256) {
    uint32_t fi = ((uint32_t)row << 12) | (uint32_t)sIdx[t];
    sP[t] = (tf_uniform(fi) < 0.9f) ? sP[t] * inv : 0.f;
  }
  __syncthreads();
  const int col = tid & 127, h = tid >> 7;
  const float* ob = outg + (size_t)b * NTOK * DD;
  float accv = 0.f;
  for (int e = h; e < c; e += 2)
    accv += sP[e] * ob[(size_t)sIdx[e]*DD + col];
  sPart[h][col] = accv;
  __syncthreads();
  if (tid < DD) agg[(size_t)row*DD + tid] = sPart[0][tid] + sPart[1][tid];
}

// ---------------- K5: h1 = prelu(prelu(agg@Wv1)@Wv2), h1nb bf16, div write --
__global__ __launch_bounds__(256) void k_v(const float* __restrict__ agg,
    const float* __restrict__ Wv1, const float* __restrict__ Wv2,
    const float* __restrict__ av_, const float* __restrict__ a1_,
    float* __restrict__ h1o, uint16_t* __restrict__ h1nb,
    const float* __restrict__ divpart, float* __restrict__ divout) {
  __shared__ float sA[16][DD];
  __shared__ float sT[16][DD];
  const int tid = threadIdx.x;
  const size_t r0 = (size_t)blockIdx.x * 16;
  for (int i = tid; i < 16*DD/4; i += 256)
    reinterpret_cast<float4*>(&sA[0][0])[i] =
        reinterpret_cast<const float4*>(agg + r0*DD)[i];
  __syncthreads();
  const int cc = tid & 127, g = tid >> 7;
  const float av = av_[0], a1v = a1_[0];
  float t_[8] = {};
  for (int kk = 0; kk < DD; ++kk) {
    float w = Wv1[kk*DD + cc];
#pragma unroll
    for (int r = 0; r < 8; ++r) t_[r] += sA[2*r + g][kk] * w;
  }
#pragma unroll
  for (int r = 0; r < 8; ++r) { float x = t_[r]; sT[2*r+g][cc] = (x >= 0.f) ? x : av * x; }
  __syncthreads();
  float v_[8] = {};
  for (int kk = 0; kk < DD; ++kk) {
    float w = Wv2[kk*DD + cc];
#pragma unroll
    for (int r = 0; r < 8; ++r) v_[r] += sT[2*r + g][kk] * w;
  }
  __syncthreads();                 // sA reads done; reuse for h1
#pragma unroll
  for (int r = 0; r < 8; ++r) { float x = v_[r]; sA[2*r+g][cc] = (x >= 0.f) ? x : a1v * x; }
  __syncthreads();
  const int rr = tid >> 4, l = tid & 15;
  float ss = 0.f;
  for (int cix = l; cix < DD; cix += 16) { float hv = sA[rr][cix]; ss += hv*hv; }
#pragma unroll
  for (int o = 8; o; o >>= 1) ss += __shfl_xor(ss, o, 16);
  const float innv = 1.f / fmaxf(sqrtf(ss), 1e-12f);
  for (int cix = l; cix < DD; cix += 16) {
    float hv = sA[rr][cix];
    h1o[(r0+rr)*DD + cix] = hv;
    h1nb[(r0+rr)*DD + cix] = f2bf(hv * innv);
  }
  if (blockIdx.x == 0 && tid == 0) {       // deterministic div_loss finalize
    float s = 0.f;
    for (int i = 0; i < 512; ++i) s += divpart[i];
    divout[0] = s * (1.f / 8192.f);
  }
}

// ---------------- K6: partial = diff@fts2 via bf16 MFMA, no LDS, K-split x4 -
// A-frag: row = l&15 (direct global fp32 -> bf16), k = (l>>4)*8+e (contiguous)
// B-frag: col = l&15 from fts2T (k-contiguous 16B), D: row=(l>>4)*4+r, col=l&15
__global__ __launch_bounds__(256) void k_diff_mfma(const float* __restrict__ diff,
    const uint16_t* __restrict__ fts2T, float* __restrict__ part) {
  const int blk = blockIdx.x;          // 512 = 128 row-tiles x 4 k-chunks
  const int kc = blk & 3;
  const int rt = blk >> 2;             // rows rt*64 .. +63
  const int w  = threadIdx.x >> 6;     // wave 0..3 -> 16-row stripe
  const int l  = threadIdx.x & 63;
  const int rowbase = rt*64 + w*16;    // global row (0..8191)
  const int b = rowbase >> 12;
  const int node = (rowbase & (NTOK-1)) + (l & 15);
  const int kl = (l >> 4) * 8;
  const float*    dp = diff  + (size_t)b*NTOK*NTOK + (size_t)node*NTOK + kc*1024 + kl;
  const uint16_t* bp = fts2T + (size_t)b*DD*NTOK + (size_t)(l & 15)*NTOK + kc*1024 + kl;
  f32x4 acc[8];
#pragma unroll
  for (int i = 0; i < 8; ++i) acc[i] = (f32x4){0.f,0.f,0.f,0.f};
  for (int k0 = 0; k0 < 1024; k0 += 32) {
    float4 fa0 = *reinterpret_cast<const float4*>(dp + k0);
    float4 fa1 = *reinterpret_cast<const float4*>(dp + k0 + 4);
    short8v a;
    a[0]=(short)f2bf(fa0.x); a[1]=(short)f2bf(fa0.y);
    a[2]=(short)f2bf(fa0.z); a[3]=(short)f2bf(fa0.w);
    a[4]=(short)f2bf(fa1.x); a[5]=(short)f2bf(fa1.y);
    a[6]=(short)f2bf(fa1.z); a[7]=(short)f2bf(fa1.w);
#pragma unroll
    for (int cb = 0; cb < 8; ++cb) {
      short8v bb = *reinterpret_cast<const short8v*>(bp + (size_t)cb*16*NTOK + k0);
      acc[cb] = __builtin_amdgcn_mfma_f32_16x16x32_bf16(a, bb, acc[cb], 0, 0, 0);
    }
  }
  float* pp = part + (size_t)kc * (NTOK*2*DD/1);   // kc * 1048576
#pragma unroll
  for (int cb = 0; cb < 8; ++cb)
#pragma unroll
    for (int r = 0; r < 4; ++r)
      pp[(size_t)(rowbase + (l>>4)*4 + r)*DD + cb*16 + (l&15)] = acc[cb][r];
}

// ---------------- K6b: h2 = prelu(sum partials), h2o fp32 + h2nb bf16 -------
__global__ __launch_bounds__(256) void k_h2(const float* __restrict__ part,
    const float* __restrict__ a2_, float* __restrict__ h2o,
    uint16_t* __restrict__ h2nb) {
  const int tid = threadIdx.x;
  const int rr = tid >> 4, l = tid & 15;
  const size_t row = (size_t)blockIdx.x*16 + rr;
  const float a2v = a2_[0];
  float x[8]; float ss = 0.f;
#pragma unroll
  for (int j = 0; j < 8; ++j) {
    size_t off = row*DD + l + j*16;
    float s = part[off] + part[1048576+off] + part[2097152+off] + part[3145728+off];
    s = (s >= 0.f) ? s : a2v * s;
    x[j] = s; ss += s*s;
  }
#pragma unroll
  for (int o = 8; o; o >>= 1) ss += __shfl_xor(ss, o, 16);
  const float innv = 1.f / fmaxf(sqrtf(ss), 1e-12f);
#pragma unroll
  for (int j = 0; j < 8; ++j) {
    size_t off = row*DD + l + j*16;
    h2o[off] = x[j];
    h2nb[off] = f2bf(x[j] * innv);
  }
}

// ---------------- K7: ret = h1n @ h2n^T via bf16 MFMA (128x128 tiles) -------
__global__ __launch_bounds__(256) void k_ret_mfma(const uint16_t* __restrict__ h1nb,
    const uint16_t* __restrict__ h2nb, float* __restrict__ ret) {
  const int blk = blockIdx.x;          // 2048: b x it(32) x jt(32)
  const int b = blk >> 10;
  const int it = (blk >> 5) & 31, jt = blk & 31;
  const int w = threadIdx.x >> 6, l = threadIdx.x & 63;
  const int kl = (l >> 4) * 8;
  const uint16_t* ap = h1nb + (size_t)(b*NTOK + it*128 + w*32 + (l&15))*DD + kl;
  const uint16_t* bp = h2nb + (size_t)(b*NTOK + jt*128 + (l&15))*DD + kl;
  f32x4 acc[2][8];
#pragma unroll
  for (int s = 0; s < 2; ++s)
#pragma unroll
    for (int cb = 0; cb < 8; ++cb) acc[s][cb] = (f32x4){0.f,0.f,0.f,0.f};
#pragma unroll
  for (int ks = 0; ks < 4; ++ks) {
    short8v a0 = *reinterpret_cast<const short8v*>(ap + ks*32);
    short8v a1 = *reinterpret_cast<const short8v*>(ap + 16*DD + ks*32);
#pragma unroll
    for (int cb = 0; cb < 8; ++cb) {
      short8v bb = *reinterpret_cast<const short8v*>(bp + (size_t)cb*16*DD + ks*32);
      acc[0][cb] = __builtin_amdgcn_mfma_f32_16x16x32_bf16(a0, bb, acc[0][cb], 0,0,0);
      acc[1][cb] = __builtin_amdgcn_mfma_f32_16x16x32_bf16(a1, bb, acc[1][cb], 0,0,0);
    }
  }
  float* rp = ret + (size_t)b*NTOK*NTOK;
#pragma unroll
  for (int s = 0; s < 2; ++s)
#pragma unroll
    for (int cb = 0; cb < 8; ++cb)
#pragma unroll
      for (int r = 0; r < 4; ++r)
        rp[(size_t)(it*128 + w*32 + s*16 + (l>>4)*4 + r)*NTOK
           + jt*128 + cb*16 + (l&15)] = acc[s][cb][r];
}

// ---------------- launch ----------------------------------------------------
extern "C" void kernel_launch(void* const* d_in, const int* in_sizes, int n_in,
                              void* d_out, int out_size, void* d_ws, size_t ws_size,
                              hipStream_t stream) {
  const float* seq1 = (const float*)d_in[0];
  const float* adj  = (const float*)d_in[2];
  const float* diff = (const float*)d_in[3];
  const float* Wfc1 = (const float*)d_in[7];
  const float* a1   = (const float*)d_in[8];
  const float* Wq   = (const float*)d_in[9];
  const float* Wk   = (const float*)d_in[10];
  const float* Wv1  = (const float*)d_in[11];
  const float* av   = (const float*)d_in[12];
  const float* Wv2  = (const float*)d_in[13];
  const float* Wfc2 = (const float*)d_in[14];
  const float* a2   = (const float*)d_in[15];
  float* out = (float*)d_out;
  float* ws  = (float*)d_ws;

  const size_t BN  = (size_t)2 * NTOK;          // 8192 rows
  const size_t RND = BN * DD;                   // 1048576
  // region [0, 5*RND): fts, fts2, outg, q, k  -- dead after k_attn;
  // partials (4*RND) overlay [0, 4*RND) for k_diff_mfma/k_h2.
  float* fts   = ws;
  float* fts2  = ws + RND;
  float* outg  = ws + 2*RND;
  float* q     = ws + 3*RND;
  float* k     = ws + 4*RND;
  float* part  = ws;                            // overlay (see ordering)
  float* agg   = ws + 5*RND;
  float* divp  = ws + 6*RND;                    // 512 floats
  int*   e_cnt = (int*)(ws + 6*RND + 512);      // 8192 ints
  int*   e_idx = (int*)(ws + 6*RND + 512 + BN); // RND ints
  uint16_t* fts2T = (uint16_t*)(ws + 7*RND + 512 + BN);      // RND ushorts
  uint16_t* h1nb  = (uint16_t*)(ws + 7*RND + 512 + BN) + RND;
  uint16_t* h2nb  = (uint16_t*)(ws + 7*RND + 512 + BN) + 2*RND;

  const size_t OFF_H1  = (size_t)2 * NTOK * NTOK;   // 33554432
  const size_t OFF_H2  = OFF_H1 + RND;              // 34603008
  const size_t OFF_DIV = OFF_H2 + RND;              // 35651584

  k_fc       <<<512,  256, 0, stream>>>(seq1, Wfc1, Wfc2, fts, fts2);
  k_prep     <<<128,  256, 0, stream>>>(fts2, fts2T);
  k_adj      <<<8192, 256, 0, stream>>>(adj, fts, outg, e_idx, e_cnt);
  k_qk       <<<512,  256, 0, stream>>>(outg, Wq, Wk, q, k, divp);
  k_attn     <<<8192, 256, 0, stream>>>(q, k, outg, e_idx, e_cnt, agg);
  k_v        <<<512,  256, 0, stream>>>(agg, Wv1, Wv2, av, a1,
                                        out + OFF_H1, h1nb, divp, out + OFF_DIV);
  k_diff_mfma<<<512,  256, 0, stream>>>(diff, fts2T, part);   // clobbers fts..q
  k_h2       <<<512,  256, 0, stream>>>(part, a2, out + OFF_H2, h2nb);
  k_ret_mfma <<<2048, 256, 0, stream>>>(h1nb, h2nb, out);
}

// Round 5
// 699.608 us; speedup vs baseline: 1.4527x; 1.0138x over previous
//
#include <hip/hip_runtime.h>
#include <cstdint>

// Problem constants (B=2, N=4096, NIN=NH=128)
#define NTOK 4096
#define DD   128
#define CAP  128   // max edges/row; binom(4096,0.01) mean 41, P(>127) ~ 1e-40

typedef __attribute__((ext_vector_type(8))) short short8v;   // 8 bf16 (4 VGPR)
typedef __attribute__((ext_vector_type(4))) float f32x4;     // MFMA C/D

__device__ __forceinline__ uint16_t f2bf(float x) {          // truncate f32->bf16
  return (uint16_t)(__float_as_uint(x) >> 16);
}

// ---------------- threefry2x32, JAX partitionable path (verified R2) --------
__device__ __forceinline__ void tf_round(uint32_t& x0, uint32_t& x1, int r) {
  x0 += x1;
  x1 = (x1 << r) | (x1 >> (32 - r));
  x1 ^= x0;
}

__device__ __forceinline__ float tf_uniform(uint32_t i) {
  const uint32_t ks1 = 42u, ks2 = 0x1BD11BF0u;
  uint32_t x0 = 0u;          // counts_hi (=0) + ks0 (=0)
  uint32_t x1 = i + ks1;     // counts_lo + ks1
  tf_round(x0,x1,13); tf_round(x0,x1,15); tf_round(x0,x1,26); tf_round(x0,x1,6);
  x0 += ks1; x1 += ks2 + 1u;
  tf_round(x0,x1,17); tf_round(x0,x1,29); tf_round(x0,x1,16); tf_round(x0,x1,24);
  x0 += ks2; x1 += 0u + 2u;
  tf_round(x0,x1,13); tf_round(x0,x1,15); tf_round(x0,x1,26); tf_round(x0,x1,6);
  x0 += 0u; x1 += ks1 + 3u;
  tf_round(x0,x1,17); tf_round(x0,x1,29); tf_round(x0,x1,16); tf_round(x0,x1,24);
  x0 += ks1; x1 += ks2 + 4u;
  tf_round(x0,x1,13); tf_round(x0,x1,15); tf_round(x0,x1,26); tf_round(x0,x1,6);
  x0 += ks2; x1 += 0u + 5u;
  uint32_t bits = x0 ^ x1;
  return __uint_as_float((bits >> 9) | 0x3F800000u) - 1.0f;
}

// ---------------- K1: fts = seq1@W_fc1, fts2 = seq1@W_fc2 (16 rows/block) ----
__global__ __launch_bounds__(256) void k_fc(const float* __restrict__ seq1,
    const float* __restrict__ W1, const float* __restrict__ W2,
    float* __restrict__ fts, float* __restrict__ fts2) {
  __shared__ float sS[16][DD];
  const int tid = threadIdx.x;
  const size_t r0 = (size_t)blockIdx.x * 16;
  for (int i = tid; i < 16*DD/4; i += 256)
    reinterpret_cast<float4*>(&sS[0][0])[i] =
        reinterpret_cast<const float4*>(seq1 + r0*DD)[i];
  __syncthreads();
  const int cc = tid & 127, g = tid >> 7;
  float a1_[8] = {}, a2_[8] = {};
  for (int kk = 0; kk < DD; ++kk) {
    float w1 = W1[kk*DD + cc], w2 = W2[kk*DD + cc];
#pragma unroll
    for (int r = 0; r < 8; ++r) {
      float sv = sS[2*r + g][kk];
      a1_[r] += sv * w1; a2_[r] += sv * w2;
    }
  }
#pragma unroll
  for (int r = 0; r < 8; ++r) {
    fts [(r0 + 2*r + g)*DD + cc] = a1_[r];
    fts2[(r0 + 2*r + g)*DD + cc] = a2_[r];
  }
}

// ---------------- K1b: fts2T[b][col][k] bf16 <- fts2[b][k][col] fp32 --------
__global__ __launch_bounds__(256) void k_prep(const float* __restrict__ fts2,
    uint16_t* __restrict__ fts2T) {
  __shared__ uint16_t sT[DD][72];     // 72-ushort stride: 144B = 9*16B aligned
  const int blk = blockIdx.x;         // 128 = b(2) x 64 node-tiles
  const int b = blk >> 6, nt = blk & 63;
  const int tid = threadIdx.x;
  const float* src = fts2 + ((size_t)b*NTOK + nt*64)*DD;
  for (int i = tid; i < 64*DD/4; i += 256) {
    int nd = i >> 5, c4 = (i & 31) * 4;
    float4 v = *reinterpret_cast<const float4*>(src + nd*DD + c4);
    sT[c4+0][nd] = f2bf(v.x); sT[c4+1][nd] = f2bf(v.y);
    sT[c4+2][nd] = f2bf(v.z); sT[c4+3][nd] = f2bf(v.w);
  }
  __syncthreads();
  for (int i = tid; i < 1024; i += 256) {
    int col = i >> 3, p = i & 7;
    *reinterpret_cast<int4*>(fts2T + ((size_t)b*DD + col)*NTOK + nt*64 + p*8) =
        *reinterpret_cast<const int4*>(&sT[col][p*8]);
  }
}

// ---------------- K2: edge extraction (deterministic, sorted) + out=adj@fts --
__global__ __launch_bounds__(256) void k_adj(const float* __restrict__ adj,
    const float* __restrict__ fts, float* __restrict__ outg,
    int* __restrict__ e_idx, int* __restrict__ e_cnt) {
  const int row = blockIdx.x;            // b*N + m
  const int b = row >> 12;
  const int tid = threadIdx.x;
  __shared__ float sA[NTOK];
  __shared__ int   sc[256];
  __shared__ int   sIdx[CAP];
  __shared__ float sVal[CAP];
  __shared__ float sPart[2][DD];
  const float* arow = adj + (size_t)row * NTOK;
  for (int i = tid; i < NTOK/4; i += 256)
    reinterpret_cast<float4*>(sA)[i] = reinterpret_cast<const float4*>(arow)[i];
  __syncthreads();
  const int base = tid * 16;
  int cnt = 0;
#pragma unroll
  for (int j = 0; j < 16; ++j) cnt += (sA[base + j] > 0.f) ? 1 : 0;
  sc[tid] = cnt;
  __syncthreads();
  for (int off = 1; off < 256; off <<= 1) {   // Hillis-Steele inclusive scan
    int v = (tid >= off) ? sc[tid - off] : 0;
    __syncthreads();
    sc[tid] += v;
    __syncthreads();
  }
  int w = sc[tid] - cnt;
  const int total = sc[255];
  const int c = min(total, CAP);
#pragma unroll
  for (int j = 0; j < 16; ++j) {
    float a = sA[base + j];
    if (a > 0.f) { if (w < CAP) { sIdx[w] = base + j; sVal[w] = a; } ++w; }
  }
  __syncthreads();
  if (tid == 0) e_cnt[row] = c;
  for (int t = tid; t < c; t += 256) e_idx[(size_t)row*CAP + t] = sIdx[t];
  // out row = sum_e val_e * fts[n_e, :]
  const float* fb = fts + (size_t)b * NTOK * DD;
  const int col = tid & 127, h = tid >> 7;
  float accv = 0.f;
  for (int e = h; e < c; e += 2)
    accv += sVal[e] * fb[(size_t)sIdx[e]*DD + col];
  sPart[h][col] = accv;
  __syncthreads();
  if (tid < DD) outg[(size_t)row*DD + tid] = sPart[0][tid] + sPart[1][tid];
}

// ---------------- K3: q,k = l2norm(out@Wq/Wk), div partials (16 rows/block) --
__global__ __launch_bounds__(256) void k_qk(const float* __restrict__ outg,
    const float* __restrict__ Wq, const float* __restrict__ Wk,
    float* __restrict__ qo, float* __restrict__ ko,
    float* __restrict__ divpart) {
  __shared__ float sO[16][DD], sQ[16][DD], sK[16][DD];
  __shared__ float sDv[16];
  const int tid = threadIdx.x;
  const size_t r0 = (size_t)blockIdx.x * 16;
  for (int i = tid; i < 16*DD/4; i += 256)
    reinterpret_cast<float4*>(&sO[0][0])[i] =
        reinterpret_cast<const float4*>(outg + r0*DD)[i];
  __syncthreads();
  const int cc = tid & 127, g = tid >> 7;
  float aq[8] = {}, ak[8] = {};
  for (int kk = 0; kk < DD; ++kk) {
    float wq = Wq[kk*DD + cc], wk = Wk[kk*DD + cc];
#pragma unroll
    for (int r = 0; r < 8; ++r) {
      float ov = sO[2*r + g][kk];
      aq[r] += ov * wq; ak[r] += ov * wk;
    }
  }
#pragma unroll
  for (int r = 0; r < 8; ++r) { sQ[2*r+g][cc] = aq[r]; sK[2*r+g][cc] = ak[r]; }
  __syncthreads();
  const int rr = tid >> 4, l = tid & 15;
  float sq = 0.f, sk = 0.f;
  for (int cix = l; cix < DD; cix += 16) {
    float qv = sQ[rr][cix], kv = sK[rr][cix];
    sq += qv*qv; sk += kv*kv;
  }
#pragma unroll
  for (int o = 8; o; o >>= 1) { sq += __shfl_xor(sq, o, 16); sk += __shfl_xor(sk, o, 16); }
  const float iq = 1.f / fmaxf(sqrtf(sq), 1e-12f);
  const float ik = 1.f / fmaxf(sqrtf(sk), 1e-12f);
  float dv = 0.f;
  for (int cix = l; cix < DD; cix += 16) {
    float qn = sQ[rr][cix] * iq, kn = sK[rr][cix] * ik;
    qo[(r0+rr)*DD + cix] = qn;
    ko[(r0+rr)*DD + cix] = kn;
    float d = qn - kn; dv += d*d;
  }
#pragma unroll
  for (int o = 8; o; o >>= 1) dv += __shfl_xor(dv, o, 16);
  if (l == 0) sDv[rr] = dv;
  __syncthreads();
  if (tid == 0) {
    float s = 0.f;
#pragma unroll
    for (int r = 0; r < 16; ++r) s += sDv[r];
    divpart[blockIdx.x] = s;  // deterministic: per-block slot, summed later
  }
}

// ---------------- K4: sparse masked softmax + dropout + agg = attn@out ------
__global__ __launch_bounds__(256) void k_attn(const float* __restrict__ qo,
    const float* __restrict__ ko, const float* __restrict__ outg,
    const int* __restrict__ e_idx, const int* __restrict__ e_cnt,
    float* __restrict__ agg) {
  const int row = blockIdx.x;
  const int b = row >> 12;
  const int tid = threadIdx.x;
  __shared__ float sQ[DD];
  __shared__ int   sIdx[CAP];
  __shared__ float sP[CAP];
  __shared__ float sSum;
  __shared__ float sPart[2][DD];
  const int c = min(e_cnt[row], CAP);
  if (tid < DD) sQ[tid] = qo[(size_t)row*DD + tid];
  for (int t = tid; t < c; t += 256) sIdx[t] = e_idx[(size_t)row*CAP + t];
  __syncthreads();
  const int wv = tid >> 6, ln = tid & 63;
  const float* kb = ko + (size_t)b * NTOK * DD;
  for (int e = wv; e < c; e += 4) {          // one wave per edge dot
    const float* kr = kb + (size_t)sIdx[e] * DD;
    float p = sQ[2*ln] * kr[2*ln] + sQ[2*ln+1] * kr[2*ln+1];
#pragma unroll
    for (int o = 32; o; o >>= 1) p += __shfl_xor(p, o, 64);
    if (ln == 0) sP[e] = p;
  }
  __syncthreads();
  if (wv == 0) {                             // softmax max+sum by wave 0
    float mx = -3.0e38f;
    for (int e = ln; e < c; e += 64) mx = fmaxf(mx, sP[e]);
#pragma unroll
    for (int o = 32; o; o >>= 1) mx = fmaxf(mx, __shfl_xor(mx, o, 64));
    float sum = 0.f;
    for (int e = ln; e < c; e += 64) { float ex = expf(sP[e] - mx); sP[e] = ex; sum += ex; }
#pragma unroll
    for (int o = 32; o; o >>= 1) sum += __shfl_xor(sum, o, 64);
    if (ln == 0) sSum = sum;
  }
  __syncthreads();
  const float inv = 1.f / (sSum * 0.9f);     // softmax /sum, dropout /0.9
  for (int t = tid; t < c; t += 256) {
    uint32_t fi = ((uint32_t)row << 12) | (uint32_t)sIdx[t];
    sP[t] = (tf_uniform(fi) < 0.9f) ? sP[t] * inv : 0.f;
  }
  __syncthreads();
  const int col = tid & 127, h = tid >> 7;
  const float* ob = outg + (size_t)b * NTOK * DD;
  float accv = 0.f;
  for (int e = h; e < c; e += 2)
    accv += sP[e] * ob[(size_t)sIdx[e]*DD + col];
  sPart[h][col] = accv;
  __syncthreads();
  if (tid < DD) agg[(size_t)row*DD + tid] = sPart[0][tid] + sPart[1][tid];
}

// ---------------- K5: h1 = prelu(prelu(agg@Wv1)@Wv2), h1nb bf16, div write --
__global__ __launch_bounds__(256) void k_v(const float* __restrict__ agg,
    const float* __restrict__ Wv1, const float* __restrict__ Wv2,
    const float* __restrict__ av_, const float* __restrict__ a1_,
    float* __restrict__ h1o, uint16_t* __restrict__ h1nb,
    const float* __restrict__ divpart, float* __restrict__ divout) {
  __shared__ float sA[16][DD];
  __shared__ float sT[16][DD];
  const int tid = threadIdx.x;
  const size_t r0 = (size_t)blockIdx.x * 16;
  for (int i = tid; i < 16*DD/4; i += 256)
    reinterpret_cast<float4*>(&sA[0][0])[i] =
        reinterpret_cast<const float4*>(agg + r0*DD)[i];
  __syncthreads();
  const int cc = tid & 127, g = tid >> 7;
  const float av = av_[0], a1v = a1_[0];
  float t_[8] = {};
  for (int kk = 0; kk < DD; ++kk) {
    float w = Wv1[kk*DD + cc];
#pragma unroll
    for (int r = 0; r < 8; ++r) t_[r] += sA[2*r + g][kk] * w;
  }
#pragma unroll
  for (int r = 0; r < 8; ++r) { float x = t_[r]; sT[2*r+g][cc] = (x >= 0.f) ? x : av * x; }
  __syncthreads();
  float v_[8] = {};
  for (int kk = 0; kk < DD; ++kk) {
    float w = Wv2[kk*DD + cc];
#pragma unroll
    for (int r = 0; r < 8; ++r) v_[r] += sT[2*r + g][kk] * w;
  }
  __syncthreads();                 // sA reads done; reuse for h1
#pragma unroll
  for (int r = 0; r < 8; ++r) { float x = v_[r]; sA[2*r+g][cc] = (x >= 0.f) ? x : a1v * x; }
  __syncthreads();
  const int rr = tid >> 4, l = tid & 15;
  float ss = 0.f;
  for (int cix = l; cix < DD; cix += 16) { float hv = sA[rr][cix]; ss += hv*hv; }
#pragma unroll
  for (int o = 8; o; o >>= 1) ss += __shfl_xor(ss, o, 16);
  const float innv = 1.f / fmaxf(sqrtf(ss), 1e-12f);
  for (int cix = l; cix < DD; cix += 16) {
    float hv = sA[rr][cix];
    h1o[(r0+rr)*DD + cix] = hv;
    h1nb[(r0+rr)*DD + cix] = f2bf(hv * innv);
  }
  if (blockIdx.x == 0 && tid == 0) {       // deterministic div_loss finalize
    float s = 0.f;
    for (int i = 0; i < 512; ++i) s += divpart[i];
    divout[0] = s * (1.f / 8192.f);
  }
}

// ---------------- K6: partial = diff@fts2 via bf16 MFMA, reg-pipelined ------
// A-frag: row = l&15 (direct global fp32 -> bf16), k = (l>>4)*8+e (contiguous)
// B-frag: col = l&15 from fts2T (k-contiguous 16B), D: row=(l>>4)*4+r, col=l&15
// Depth-2 rotating 3-buffer prefetch: issue group g+2's 8 KB/wave of A-loads
// before computing group g; keeps ~16 KB/wave in flight -> BW-bound not
// latency-bound. All indices compile-time (full unroll) to stay in registers.
__device__ __forceinline__ void load_group(const float* __restrict__ dp,
                                           int g, float4* buf) {
#pragma unroll
  for (int s = 0; s < 4; ++s) {
    buf[2*s]   = *reinterpret_cast<const float4*>(dp + g*128 + s*32);
    buf[2*s+1] = *reinterpret_cast<const float4*>(dp + g*128 + s*32 + 4);
  }
}

__device__ __forceinline__ void comp_group(const uint16_t* __restrict__ bp,
    int g, const float4* buf, f32x4* acc) {
#pragma unroll
  for (int s = 0; s < 4; ++s) {
    const float4 f0 = buf[2*s], f1 = buf[2*s+1];
    short8v a;
    a[0]=(short)f2bf(f0.x); a[1]=(short)f2bf(f0.y);
    a[2]=(short)f2bf(f0.z); a[3]=(short)f2bf(f0.w);
    a[4]=(short)f2bf(f1.x); a[5]=(short)f2bf(f1.y);
    a[6]=(short)f2bf(f1.z); a[7]=(short)f2bf(f1.w);
#pragma unroll
    for (int cb = 0; cb < 8; ++cb) {
      short8v bb = *reinterpret_cast<const short8v*>(
          bp + (size_t)cb*16*NTOK + g*128 + s*32);
      acc[cb] = __builtin_amdgcn_mfma_f32_16x16x32_bf16(a, bb, acc[cb], 0, 0, 0);
    }
  }
}

__global__ __launch_bounds__(256) void k_diff_mfma(const float* __restrict__ diff,
    const uint16_t* __restrict__ fts2T, float* __restrict__ part) {
  const int blk = blockIdx.x;          // 512 = 128 row-tiles x 4 k-chunks
  const int kc = blk & 3;
  const int rt = blk >> 2;             // rows rt*64 .. +63
  const int w  = threadIdx.x >> 6;     // wave 0..3 -> 16-row stripe
  const int l  = threadIdx.x & 63;
  const int rowbase = rt*64 + w*16;    // global row (0..8191)
  const int b = rowbase >> 12;
  const int node = (rowbase & (NTOK-1)) + (l & 15);
  const int kl = (l >> 4) * 8;
  const float*    dp = diff  + (size_t)b*NTOK*NTOK + (size_t)node*NTOK + kc*1024 + kl;
  const uint16_t* bp = fts2T + (size_t)b*DD*NTOK + (size_t)(l & 15)*NTOK + kc*1024 + kl;
  f32x4 acc[8];
#pragma unroll
  for (int i = 0; i < 8; ++i) acc[i] = (f32x4){0.f,0.f,0.f,0.f};
  float4 buf[3][8];
  load_group(dp, 0, buf[0]);
  load_group(dp, 1, buf[1]);
#pragma unroll
  for (int g = 0; g < 8; ++g) {        // full unroll: static buf indices
    if (g + 2 < 8) load_group(dp, g + 2, buf[(g + 2) % 3]);
    comp_group(bp, g, buf[g % 3], acc);
  }
  float* pp = part + (size_t)kc * 1048576;
#pragma unroll
  for (int cb = 0; cb < 8; ++cb)
#pragma unroll
    for (int r = 0; r < 4; ++r)
      pp[(size_t)(rowbase + (l>>4)*4 + r)*DD + cb*16 + (l&15)] = acc[cb][r];
}

// ---------------- K6b: h2 = prelu(sum partials), h2o fp32 + h2nb bf16 -------
__global__ __launch_bounds__(256) void k_h2(const float* __restrict__ part,
    const float* __restrict__ a2_, float* __restrict__ h2o,
    uint16_t* __restrict__ h2nb) {
  const int tid = threadIdx.x;
  const int rr = tid >> 4, l = tid & 15;
  const size_t row = (size_t)blockIdx.x*16 + rr;
  const float a2v = a2_[0];
  float x[8]; float ss = 0.f;
#pragma unroll
  for (int j = 0; j < 8; ++j) {
    size_t off = row*DD + l + j*16;
    float s = part[off] + part[1048576+off] + part[2097152+off] + part[3145728+off];
    s = (s >= 0.f) ? s : a2v * s;
    x[j] = s; ss += s*s;
  }
#pragma unroll
  for (int o = 8; o; o >>= 1) ss += __shfl_xor(ss, o, 16);
  const float innv = 1.f / fmaxf(sqrtf(ss), 1e-12f);
#pragma unroll
  for (int j = 0; j < 8; ++j) {
    size_t off = row*DD + l + j*16;
    h2o[off] = x[j];
    h2nb[off] = f2bf(x[j] * innv);
  }
}

// ---------------- K7: ret = h1n @ h2n^T via bf16 MFMA (128x128 tiles) -------
__global__ __launch_bounds__(256) void k_ret_mfma(const uint16_t* __restrict__ h1nb,
    const uint16_t* __restrict__ h2nb, float* __restrict__ ret) {
  const int blk = blockIdx.x;          // 2048: b x it(32) x jt(32)
  const int b = blk >> 10;
  const int it = (blk >> 5) & 31, jt = blk & 31;
  const int w = threadIdx.x >> 6, l = threadIdx.x & 63;
  const int kl = (l >> 4) * 8;
  const uint16_t* ap = h1nb + (size_t)(b*NTOK + it*128 + w*32 + (l&15))*DD + kl;
  const uint16_t* bp = h2nb + (size_t)(b*NTOK + jt*128 + (l&15))*DD + kl;
  f32x4 acc[2][8];
#pragma unroll
  for (int s = 0; s < 2; ++s)
#pragma unroll
    for (int cb = 0; cb < 8; ++cb) acc[s][cb] = (f32x4){0.f,0.f,0.f,0.f};
#pragma unroll
  for (int ks = 0; ks < 4; ++ks) {
    short8v a0 = *reinterpret_cast<const short8v*>(ap + ks*32);
    short8v a1 = *reinterpret_cast<const short8v*>(ap + 16*DD + ks*32);
#pragma unroll
    for (int cb = 0; cb < 8; ++cb) {
      short8v bb = *reinterpret_cast<const short8v*>(bp + (size_t)cb*16*DD + ks*32);
      acc[0][cb] = __builtin_amdgcn_mfma_f32_16x16x32_bf16(a0, bb, acc[0][cb], 0,0,0);
      acc[1][cb] = __builtin_amdgcn_mfma_f32_16x16x32_bf16(a1, bb, acc[1][cb], 0,0,0);
    }
  }
  float* rp = ret + (size_t)b*NTOK*NTOK;
#pragma unroll
  for (int s = 0; s < 2; ++s)
#pragma unroll
    for (int cb = 0; cb < 8; ++cb)
#pragma unroll
      for (int r = 0; r < 4; ++r)
        rp[(size_t)(it*128 + w*32 + s*16 + (l>>4)*4 + r)*NTOK
           + jt*128 + cb*16 + (l&15)] = acc[s][cb][r];
}

// ---------------- launch ----------------------------------------------------
extern "C" void kernel_launch(void* const* d_in, const int* in_sizes, int n_in,
                              void* d_out, int out_size, void* d_ws, size_t ws_size,
                              hipStream_t stream) {
  const float* seq1 = (const float*)d_in[0];
  const float* adj  = (const float*)d_in[2];
  const float* diff = (const float*)d_in[3];
  const float* Wfc1 = (const float*)d_in[7];
  const float* a1   = (const float*)d_in[8];
  const float* Wq   = (const float*)d_in[9];
  const float* Wk   = (const float*)d_in[10];
  const float* Wv1  = (const float*)d_in[11];
  const float* av   = (const float*)d_in[12];
  const float* Wv2  = (const float*)d_in[13];
  const float* Wfc2 = (const float*)d_in[14];
  const float* a2   = (const float*)d_in[15];
  float* out = (float*)d_out;
  float* ws  = (float*)d_ws;

  const size_t BN  = (size_t)2 * NTOK;          // 8192 rows
  const size_t RND = BN * DD;                   // 1048576
  // region [0, 5*RND): fts, fts2, outg, q, k  -- dead after k_attn;
  // partials (4*RND) overlay [0, 4*RND) for k_diff_mfma/k_h2.
  float* fts   = ws;
  float* fts2  = ws + RND;
  float* outg  = ws + 2*RND;
  float* q     = ws + 3*RND;
  float* k     = ws + 4*RND;
  float* part  = ws;                            // overlay (see ordering)
  float* agg   = ws + 5*RND;
  float* divp  = ws + 6*RND;                    // 512 floats
  int*   e_cnt = (int*)(ws + 6*RND + 512);      // 8192 ints
  int*   e_idx = (int*)(ws + 6*RND + 512 + BN); // RND ints
  uint16_t* fts2T = (uint16_t*)(ws + 7*RND + 512 + BN);      // RND ushorts
  uint16_t* h1nb  = (uint16_t*)(ws + 7*RND + 512 + BN) + RND;
  uint16_t* h2nb  = (uint16_t*)(ws + 7*RND + 512 + BN) + 2*RND;

  const size_t OFF_H1  = (size_t)2 * NTOK * NTOK;   // 33554432
  const size_t OFF_H2  = OFF_H1 + RND;              // 34603008
  const size_t OFF_DIV = OFF_H2 + RND;              // 35651584

  k_fc       <<<512,  256, 0, stream>>>(seq1, Wfc1, Wfc2, fts, fts2);
  k_prep     <<<128,  256, 0, stream>>>(fts2, fts2T);
  k_adj      <<<8192, 256, 0, stream>>>(adj, fts, outg, e_idx, e_cnt);
  k_qk       <<<512,  256, 0, stream>>>(outg, Wq, Wk, q, k, divp);
  k_attn     <<<8192, 256, 0, stream>>>(q, k, outg, e_idx, e_cnt, agg);
  k_v        <<<512,  256, 0, stream>>>(agg, Wv1, Wv2, av, a1,
                                        out + OFF_H1, h1nb, divp, out + OFF_DIV);
  k_diff_mfma<<<512,  256, 0, stream>>>(diff, fts2T, part);   // clobbers fts..q
  k_h2       <<<512,  256, 0, stream>>>(part, a2, out + OFF_H2, h2nb);
  k_ret_mfma <<<2048, 256, 0, stream>>>(h1nb, h2nb, out);
}